// Round 2
// baseline (2675.239 us; speedup 1.0000x reference)
//
#include <hip/hip_runtime.h>

#define BB 16
#define DD 512
#define TT 4096
#define KK 1024
#define NN (BB*TT)              // 65536 rows
#define ROWS 64                 // t-rows per block
#define BLOCKT 512              // 8 waves
#define NWAVES 8
#define CODES_PER_WAVE (KK/NWAVES)  // 128
#define CHUNK 8
#define XS_LD 65                // padded leading dim for x tile
#define MARGIN 4e-4f            // candidate-collection margin (>=3x perturbation bound)
#define CMAX 8                  // max refine candidates per row
#define PMAX 512                // max refine pairs per block

// ---- numpy pairwise-sum replication (fp32, squares of elements) ----
// Model: contiguous fp32 np.sum, SIMD W=16 (AVX512), 8 vector accumulators,
// gcc _mm512_reduce_add_ps tree. 512 elems -> recursive split into 4x128.
__device__ __forceinline__ float pw128_sq_strided(const float* a, int stride) {
    float V[16];
    #pragma unroll
    for (int l = 0; l < 16; ++l) {
        float q[8];
        #pragma unroll
        for (int k = 0; k < 8; ++k) {
            float e = a[(l + 16 * k) * stride];
            q[k] = __fmul_rn(e, e);
        }
        // ((r0+r1)+(r2+r3)) + ((r4+r5)+(r6+r7)) per lane
        V[l] = __fadd_rn(__fadd_rn(__fadd_rn(q[0], q[1]), __fadd_rn(q[2], q[3])),
                         __fadd_rn(__fadd_rn(q[4], q[5]), __fadd_rn(q[6], q[7])));
    }
    // gcc _mm512_reduce_add_ps tree
    float u[8];
    #pragma unroll
    for (int l = 0; l < 8; ++l) u[l] = __fadd_rn(V[l], V[l + 8]);
    float v[4];
    #pragma unroll
    for (int l = 0; l < 4; ++l) v[l] = __fadd_rn(u[l], u[l + 4]);
    float w0 = __fadd_rn(v[0], v[2]);
    float w1 = __fadd_rn(v[1], v[3]);
    return __fadd_rn(w0, w1);
}

__device__ __forceinline__ float pw512_sq_strided(const float* a, int stride) {
    float p0 = pw128_sq_strided(a, stride);
    float p1 = pw128_sq_strided(a + 128 * stride, stride);
    float p2 = pw128_sq_strided(a + 256 * stride, stride);
    float p3 = pw128_sq_strided(a + 384 * stride, stride);
    return __fadd_rn(__fadd_rn(p0, p1), __fadd_rn(p2, p3));
}

// ---------------- exact ||e||^2 per code row ----------------
__global__ void enorms_exact(const float* __restrict__ E, float* __restrict__ se) {
    int i = blockIdx.x * blockDim.x + threadIdx.x;
    if (i < KK) se[i] = pw512_sq_strided(E + (long)i * DD, 1);
}

// ---------------- main kernel ----------------
__global__ __launch_bounds__(BLOCKT, 1)
void vq_main(const float* __restrict__ x, const float* __restrict__ E,
             const float* __restrict__ se, double* __restrict__ loss_acc,
             float* __restrict__ out) {
    __shared__ float xs[DD * XS_LD];            // 133,120 B  x tile [j][row]
    __shared__ float smv[NWAVES * ROWS * 2];    // per-wave top2 values
    __shared__ int   smi[NWAVES * ROWS * 2];    // per-wave top2 indices
    __shared__ float Pp[4 * ROWS];              // per-row pairwise 128-block partials
    __shared__ float sxs[ROWS];                 // exact ||x||^2 per row
    __shared__ int   prow[PMAX];                // refine pair: row
    __shared__ int   pcand[PMAX];               // refine pair: candidate
    __shared__ float pdist[PMAX];               // refine pair: exact fp32 dist
    __shared__ int   pcnt;
    __shared__ int   fidx[ROWS];

    const int tid = threadIdx.x;
    const int blk = blockIdx.x;
    const int b  = blk >> 6;                    // 64 blocks per batch
    const int t0 = (blk & 63) * ROWS;
    const long nbase = (long)b * TT + t0;

    // ---- stage x[b][j][t0..t0+63] into LDS (coalesced along t) ----
    const float* xb = x + (long)b * DD * TT + t0;
    #pragma unroll
    for (int it = 0; it < 16; ++it) {
        int flat = it * BLOCKT + tid;           // 16 float4 per j-row
        int j  = flat >> 4;
        int t4 = (flat & 15) * 4;
        float4 v = *reinterpret_cast<const float4*>(xb + (long)j * TT + t4);
        float* dst = &xs[j * XS_LD + t4];
        dst[0] = v.x; dst[1] = v.y; dst[2] = v.z; dst[3] = v.w;
    }
    if (tid == 0) pcnt = 0;
    __syncthreads();

    // ---- exact pairwise partials for ||x||^2 (4 threads per row) ----
    if (tid < 4 * ROWS) {
        int r = tid & 63, k = tid >> 6;
        Pp[k * ROWS + r] = pw128_sq_strided(&xs[r] + (k * 128) * XS_LD, XS_LD);
    }

    const int w    = __builtin_amdgcn_readfirstlane(tid >> 6);
    const int lane = tid & 63;                  // lane == row

    // ---- fp32 filter pass: s_i = ||e_i||^2 - 2 x.e_i ; keep top-2/wave ----
    float m1 = 1e30f, m2 = 1e30f;
    int   i1 = 0,     i2 = 0;
    const int cbase = w * CODES_PER_WAVE;
    for (int ch = 0; ch < CODES_PER_WAVE; ch += CHUNK) {
        const int i0 = cbase + ch;
        const float* Ep = E + (long)i0 * DD;
        float acc[CHUNK];
        #pragma unroll
        for (int c = 0; c < CHUNK; ++c) acc[c] = 0.f;
        for (int j = 0; j < DD; j += 4) {
            float x0 = xs[(j + 0) * XS_LD + lane];
            float x1 = xs[(j + 1) * XS_LD + lane];
            float x2 = xs[(j + 2) * XS_LD + lane];
            float x3 = xs[(j + 3) * XS_LD + lane];
            #pragma unroll
            for (int c = 0; c < CHUNK; ++c) {
                float4 e4 = *reinterpret_cast<const float4*>(&Ep[c * DD + j]);
                acc[c] = fmaf(x0, e4.x, acc[c]);
                acc[c] = fmaf(x1, e4.y, acc[c]);
                acc[c] = fmaf(x2, e4.z, acc[c]);
                acc[c] = fmaf(x3, e4.w, acc[c]);
            }
        }
        #pragma unroll
        for (int c = 0; c < CHUNK; ++c) {
            float s = fmaf(-2.f, acc[c], se[i0 + c]);
            int ii = i0 + c;
            if (s < m1)      { m2 = m1; i2 = i1; m1 = s; i1 = ii; }
            else if (s < m2) { m2 = s;  i2 = ii; }
        }
    }
    smv[(w * ROWS + lane) * 2 + 0] = m1;
    smv[(w * ROWS + lane) * 2 + 1] = m2;
    smi[(w * ROWS + lane) * 2 + 0] = i1;
    smi[(w * ROWS + lane) * 2 + 1] = i2;
    __syncthreads();

    // ---- merge, compute exact sx, collect within-margin candidates ----
    if (tid < ROWS) {
        float sx = __fadd_rn(__fadd_rn(Pp[0 * ROWS + tid], Pp[1 * ROWS + tid]),
                             __fadd_rn(Pp[2 * ROWS + tid], Pp[3 * ROWS + tid]));
        sxs[tid] = sx;
        float m = 1e30f;
        for (int e = 0; e < NWAVES * 2; ++e) {
            float s = smv[((e >> 1) * ROWS + tid) * 2 + (e & 1)];
            if (s < m) m = s;
        }
        float thr = m + MARGIN;
        int pushed = 0;
        for (int e = 0; e < NWAVES * 2 && pushed < CMAX; ++e) {
            float s = smv[((e >> 1) * ROWS + tid) * 2 + (e & 1)];
            if (s <= thr) {
                int pos = atomicAdd(&pcnt, 1);
                if (pos < PMAX) {
                    prow[pos]  = tid;
                    pcand[pos] = smi[((e >> 1) * ROWS + tid) * 2 + (e & 1)];
                    ++pushed;
                }
            }
        }
    }
    __syncthreads();

    // ---- exact fp32 replay per candidate (numpy semantics) ----
    const int npairs = (pcnt < PMAX) ? pcnt : PMAX;
    if (tid < npairs) {
        int r = prow[tid], c = pcand[tid];
        const float* Ep = E + (long)c * DD;
        float g = 0.f;                          // sequential k-ascending FMA chain
        #pragma unroll 8
        for (int j = 0; j < DD; ++j)
            g = __fmaf_rn(xs[j * XS_LD + r], Ep[j], g);
        float t1 = __fadd_rn(sxs[r], se[c]);    // fl32(sx + se)
        pdist[tid] = __fsub_rn(t1, __fmul_rn(2.f, g));  // fl32(t1 - 2g)
    }
    __syncthreads();

    // ---- per-row argmin with first-occurrence tie-break ----
    if (tid < ROWS) {
        float bd = 1e30f; int bi = KK;
        for (int p = 0; p < npairs; ++p) {
            if (prow[p] != tid) continue;
            float d = pdist[p]; int c = pcand[p];
            if (d < bd || (d == bd && c < bi)) { bd = d; bi = c; }
        }
        fidx[tid] = bi;
        out[(size_t)NN * DD + 1 + nbase + tid] = (float)bi;
    }
    __syncthreads();

    // ---- gather rows, replicate quantized_st = fl(x + fl(q-x)), loss ----
    double lacc = 0.0;
    #pragma unroll
    for (int it = 0; it < 16; ++it) {
        int flat = it * BLOCKT + tid;           // 8192 float4 = 64 rows * 128
        int r = flat >> 7;
        int j = (flat & 127) * 4;
        int idx = fidx[r];
        float4 ev = *reinterpret_cast<const float4*>(E + (long)idx * DD + j);
        float xv0 = xs[(j + 0) * XS_LD + r];
        float xv1 = xs[(j + 1) * XS_LD + r];
        float xv2 = xs[(j + 2) * XS_LD + r];
        float xv3 = xs[(j + 3) * XS_LD + r];
        float d0 = __fsub_rn(ev.x, xv0);
        float d1 = __fsub_rn(ev.y, xv1);
        float d2 = __fsub_rn(ev.z, xv2);
        float d3 = __fsub_rn(ev.w, xv3);
        float4 st;
        st.x = __fadd_rn(xv0, d0);
        st.y = __fadd_rn(xv1, d1);
        st.z = __fadd_rn(xv2, d2);
        st.w = __fadd_rn(xv3, d3);
        *reinterpret_cast<float4*>(out + (size_t)(nbase + r) * DD + j) = st;
        lacc += (double)d0 * d0 + (double)d1 * d1 + (double)d2 * d2 + (double)d3 * d3;
    }
    #pragma unroll
    for (int off = 32; off; off >>= 1) lacc += __shfl_down(lacc, off, 64);
    if (lane == 0) atomicAdd(loss_acc, lacc);
}

// ---------------- loss finalize ----------------
__global__ void finalize_kernel(const double* __restrict__ loss_acc, float* __restrict__ out) {
    if (threadIdx.x == 0 && blockIdx.x == 0) {
        // loss = 0.25*mean + 1.0*mean = 1.25 * mean((q - x)^2)
        out[(size_t)NN * DD] = (float)(1.25 * (*loss_acc) / ((double)NN * DD));
    }
}

extern "C" void kernel_launch(void* const* d_in, const int* in_sizes, int n_in,
                              void* d_out, int out_size, void* d_ws, size_t ws_size,
                              hipStream_t stream) {
    const float* x = (const float*)d_in[0];
    const float* E = (const float*)d_in[1];
    float* out = (float*)d_out;
    double* loss_acc = (double*)d_ws;                       // 8 B
    float* se = (float*)((char*)d_ws + 64);                 // 4 KB exact ||e||^2

    hipMemsetAsync(d_ws, 0, 64, stream);                    // zero loss accumulator
    enorms_exact<<<4, 256, 0, stream>>>(E, se);
    vq_main<<<NN / ROWS, BLOCKT, 0, stream>>>(x, E, se, loss_acc, out);
    finalize_kernel<<<1, 64, 0, stream>>>(loss_acc, out);
}

// Round 3
// 534.059 us; speedup vs baseline: 5.0093x; 5.0093x over previous
//
#include <hip/hip_runtime.h>

#define BB 16
#define DD 512
#define TT 4096
#define KK 1024
#define NN (BB*TT)              // 65536 rows
#define ROWS 64                 // t-rows per block
#define BLOCKT 512              // 8 waves
#define NWAVES 8
#define MARGIN 4e-4f            // candidate-collection margin
#define CMAX 8                  // max refine candidates per row
#define PMAX 512                // max refine pairs per block
#define TOPW 3                  // top-k kept per wave per row

typedef __attribute__((ext_vector_type(8))) short short8v;   // 8 bf16
typedef __attribute__((ext_vector_type(4))) float f32x4;

// ---- bf16 split helpers (RNE) ----
__device__ __forceinline__ unsigned short f2bf(float f) {
    unsigned int u = __float_as_uint(f);
    unsigned int r = (u + 0x7fffu + ((u >> 16) & 1u)) >> 16;
    return (unsigned short)r;
}
__device__ __forceinline__ float bf2f(unsigned short b) {
    return __uint_as_float(((unsigned int)b) << 16);
}

// ---- numpy pairwise-sum replication (fp32, squares) — verified passing ----
__device__ __forceinline__ float pw128_sq_strided(const float* a, int stride) {
    float V[16];
    #pragma unroll
    for (int l = 0; l < 16; ++l) {
        float q[8];
        #pragma unroll
        for (int k = 0; k < 8; ++k) {
            float e = a[(l + 16 * k) * stride];
            q[k] = __fmul_rn(e, e);
        }
        V[l] = __fadd_rn(__fadd_rn(__fadd_rn(q[0], q[1]), __fadd_rn(q[2], q[3])),
                         __fadd_rn(__fadd_rn(q[4], q[5]), __fadd_rn(q[6], q[7])));
    }
    float u[8];
    #pragma unroll
    for (int l = 0; l < 8; ++l) u[l] = __fadd_rn(V[l], V[l + 8]);
    float v[4];
    #pragma unroll
    for (int l = 0; l < 4; ++l) v[l] = __fadd_rn(u[l], u[l + 4]);
    return __fadd_rn(__fadd_rn(v[0], v[2]), __fadd_rn(v[1], v[3]));
}
__device__ __forceinline__ float pw512_sq_strided(const float* a, int stride) {
    float p0 = pw128_sq_strided(a, stride);
    float p1 = pw128_sq_strided(a + 128 * stride, stride);
    float p2 = pw128_sq_strided(a + 256 * stride, stride);
    float p3 = pw128_sq_strided(a + 384 * stride, stride);
    return __fadd_rn(__fadd_rn(p0, p1), __fadd_rn(p2, p3));
}

// ---------------- exact ||e||^2 per code row ----------------
__global__ void enorms_exact(const float* __restrict__ E, float* __restrict__ se) {
    int i = blockIdx.x * blockDim.x + threadIdx.x;
    if (i < KK) se[i] = pw512_sq_strided(E + (long)i * DD, 1);
}

// ---------------- pack E into MFMA B-fragment layout (hi/lo bf16) ----------
// element (code c, k): ntile=c>>4, lane=(c&15)+((k>>3)&3)*16, kk=k>>5, j=k&7
// hw = ((ntile*16+kk)*64 + lane)*8 + j
__global__ void pack_e(const float* __restrict__ E,
                       unsigned short* __restrict__ Bph,
                       unsigned short* __restrict__ Bpl) {
    int i = blockIdx.x * blockDim.x + threadIdx.x;   // 0 .. KK*DD-1
    if (i >= KK * DD) return;
    int c = i >> 9, k = i & 511;
    float v = E[i];
    unsigned short h = f2bf(v);
    unsigned short l = f2bf(v - bf2f(h));
    int lane = (c & 15) + ((k >> 3) & 3) * 16;
    int hw = (((c >> 4) * 16 + (k >> 5)) * 64 + lane) * 8 + (k & 7);
    Bph[hw] = h;
    Bpl[hw] = l;
}

// ---------------- MFMA main kernel ----------------
__global__ __launch_bounds__(BLOCKT, 1)
void vq_mfma(const float* __restrict__ x, const float* __restrict__ E,
             const unsigned short* __restrict__ Bph,
             const unsigned short* __restrict__ Bpl,
             const float* __restrict__ se, double* __restrict__ loss_acc,
             float* __restrict__ out) {
    // union region: A-packed (hi 64K + lo 64K) during GEMM, then f32 x tile
    __shared__ __align__(16) unsigned char uni[131072];
    __shared__ float smv[NWAVES * ROWS * TOPW];
    __shared__ int   smi[NWAVES * ROWS * TOPW];
    __shared__ float Pp[4 * ROWS];
    __shared__ float sxs[ROWS];
    __shared__ int   prow[PMAX];
    __shared__ int   pcand[PMAX];
    __shared__ float pdist[PMAX];
    __shared__ int   pcnt;
    __shared__ int   fidx[ROWS];

    const int tid  = threadIdx.x;
    const int w    = tid >> 6;
    const int lane = tid & 63;
    const int blk  = blockIdx.x;
    const int b    = blk >> 6;
    const int t0   = (blk & 63) * ROWS;
    const long nbase = (long)b * TT + t0;
    const float* xb = x + (long)b * DD * TT + t0;

    unsigned short* AhiW = (unsigned short*)uni;             // 32768 hw
    unsigned short* AloW = (unsigned short*)(uni + 65536);
    float* xsf = (float*)uni;                                // after GEMM: [512][64]

    // ---- stage: x tile -> bf16 hi/lo in A-fragment-packed LDS ----
    #pragma unroll
    for (int it = 0; it < 16; ++it) {
        int flat = it * BLOCKT + tid;       // (d, r4): d = flat>>4, r4 = flat&15
        int d  = flat >> 4;
        int r4 = (flat & 15) * 4;
        float4 v = *reinterpret_cast<const float4*>(xb + (long)d * TT + r4);
        float vv[4] = {v.x, v.y, v.z, v.w};
        int kk = d >> 5, lg = (d >> 3) & 3, j = d & 7;
        #pragma unroll
        for (int i = 0; i < 4; ++i) {
            int r = r4 + i;
            int m = r >> 4;
            int lp = (r & 15) + lg * 16;
            int hw = ((m * 16 + kk) * 512) + lp * 8 + j;
            unsigned short h = f2bf(vv[i]);
            AhiW[hw] = h;
            AloW[hw] = f2bf(vv[i] - bf2f(h));
        }
    }
    if (tid == 0) pcnt = 0;
    __syncthreads();

    // ---- GEMM: dot[r][c] for this wave's 128 codes, K=512, hi/lo 3-combo ----
    f32x4 acc[4][8];
    #pragma unroll
    for (int m = 0; m < 4; ++m)
        #pragma unroll
        for (int n = 0; n < 8; ++n)
            acc[m][n] = (f32x4){0.f, 0.f, 0.f, 0.f};

    const unsigned short* Ah = (const unsigned short*)uni;
    const unsigned short* Al = (const unsigned short*)(uni + 65536);
    const short8v* Bhv = (const short8v*)Bph;
    const short8v* Blv = (const short8v*)Bpl;

    for (int kk = 0; kk < 16; ++kk) {
        short8v ah[4], al[4];
        #pragma unroll
        for (int m = 0; m < 4; ++m) {
            ah[m] = *(const short8v*)&Ah[(m * 16 + kk) * 512 + lane * 8];
            al[m] = *(const short8v*)&Al[(m * 16 + kk) * 512 + lane * 8];
        }
        #pragma unroll
        for (int n = 0; n < 8; ++n) {
            int bo = ((w * 8 + n) * 16 + kk) * 64 + lane;
            short8v bh = Bhv[bo];
            short8v bl = Blv[bo];
            #pragma unroll
            for (int m = 0; m < 4; ++m) {
                acc[m][n] = __builtin_amdgcn_mfma_f32_16x16x32_bf16(ah[m], bh, acc[m][n], 0, 0, 0);
                acc[m][n] = __builtin_amdgcn_mfma_f32_16x16x32_bf16(ah[m], bl, acc[m][n], 0, 0, 0);
                acc[m][n] = __builtin_amdgcn_mfma_f32_16x16x32_bf16(al[m], bh, acc[m][n], 0, 0, 0);
            }
        }
    }

    // ---- epilogue: scores, per-row top-3 across this wave's 128 codes ----
    // C/D layout (m89): col = lane&15, row = (lane>>4)*4 + reg
    float sef[8];
    #pragma unroll
    for (int n = 0; n < 8; ++n) sef[n] = se[w * 128 + n * 16 + (lane & 15)];

    #pragma unroll
    for (int m = 0; m < 4; ++m) {
        #pragma unroll
        for (int r4 = 0; r4 < 4; ++r4) {
            float s0 = 1e30f, s1 = 1e30f, s2 = 1e30f;
            int   i0 = 0, i1 = 0, i2 = 0;
            #pragma unroll
            for (int n = 0; n < 8; ++n) {
                float sc = fmaf(-2.f, acc[m][n][r4], sef[n]);
                int ci = w * 128 + n * 16 + (lane & 15);
                if (sc < s0)      { s2 = s1; i2 = i1; s1 = s0; i1 = i0; s0 = sc; i0 = ci; }
                else if (sc < s1) { s2 = s1; i2 = i1; s1 = sc; i1 = ci; }
                else if (sc < s2) { s2 = sc; i2 = ci; }
            }
            #pragma unroll
            for (int off = 1; off < 16; off <<= 1) {
                float t0 = __shfl_xor(s0, off, 64), t1 = __shfl_xor(s1, off, 64), t2 = __shfl_xor(s2, off, 64);
                int   j0 = __shfl_xor(i0, off, 64), j1 = __shfl_xor(i1, off, 64), j2 = __shfl_xor(i2, off, 64);
                if (t0 < s0)      { s2 = s1; i2 = i1; s1 = s0; i1 = i0; s0 = t0; i0 = j0; }
                else if (t0 < s1) { s2 = s1; i2 = i1; s1 = t0; i1 = j0; }
                else if (t0 < s2) { s2 = t0; i2 = j0; }
                if (t1 < s1)      { s2 = s1; i2 = i1; s1 = t1; i1 = j1; }
                else if (t1 < s2) { s2 = t1; i2 = j1; }
                if (t2 < s2)      { s2 = t2; i2 = j2; }
            }
            if ((lane & 15) == 0) {
                int row = m * 16 + (lane >> 4) * 4 + r4;
                int base = (w * ROWS + row) * TOPW;
                smv[base] = s0; smv[base + 1] = s1; smv[base + 2] = s2;
                smi[base] = i0; smi[base + 1] = i1; smi[base + 2] = i2;
            }
        }
    }
    __syncthreads();   // all uni reads done; smv/smi complete

    // ---- refill union LDS with f32 x tile [d=512][r=64] ----
    #pragma unroll
    for (int it = 0; it < 16; ++it) {
        int flat = it * BLOCKT + tid;
        int d  = flat >> 4;
        int r4 = (flat & 15) * 4;
        float4 v = *reinterpret_cast<const float4*>(xb + (long)d * TT + r4);
        *reinterpret_cast<float4*>(&xsf[d * 64 + r4]) = v;
    }
    __syncthreads();

    // ---- exact pairwise partials for ||x||^2 ----
    if (tid < 4 * ROWS) {
        int r = tid & 63, k = tid >> 6;
        Pp[k * ROWS + r] = pw128_sq_strided(xsf + r + (k * 128) * 64, 64);
    }
    __syncthreads();

    // ---- merge, exact sx, collect within-margin candidates ----
    if (tid < ROWS) {
        float sx = __fadd_rn(__fadd_rn(Pp[0 * ROWS + tid], Pp[1 * ROWS + tid]),
                             __fadd_rn(Pp[2 * ROWS + tid], Pp[3 * ROWS + tid]));
        sxs[tid] = sx;
        float mmin = 1e30f;
        for (int e = 0; e < NWAVES * TOPW; ++e) {
            float s = smv[((e / TOPW) * ROWS + tid) * TOPW + (e % TOPW)];
            if (s < mmin) mmin = s;
        }
        float thr = mmin + MARGIN;
        int pushed = 0;
        for (int e = 0; e < NWAVES * TOPW && pushed < CMAX; ++e) {
            float s = smv[((e / TOPW) * ROWS + tid) * TOPW + (e % TOPW)];
            if (s <= thr) {
                int pos = atomicAdd(&pcnt, 1);
                if (pos < PMAX) {
                    prow[pos]  = tid;
                    pcand[pos] = smi[((e / TOPW) * ROWS + tid) * TOPW + (e % TOPW)];
                    ++pushed;
                }
            }
        }
    }
    __syncthreads();

    // ---- exact fp32 replay per candidate (numpy semantics) ----
    const int npairs = (pcnt < PMAX) ? pcnt : PMAX;
    if (tid < npairs) {
        int r = prow[tid], c = pcand[tid];
        const float* Ep = E + (long)c * DD;
        float g = 0.f;
        #pragma unroll 8
        for (int j = 0; j < DD; ++j)
            g = __fmaf_rn(xsf[j * 64 + r], Ep[j], g);
        float t1 = __fadd_rn(sxs[r], se[c]);
        pdist[tid] = __fsub_rn(t1, __fmul_rn(2.f, g));
    }
    __syncthreads();

    // ---- per-row argmin, first-occurrence tie-break ----
    if (tid < ROWS) {
        float bd = 1e30f; int bi = KK;
        for (int p = 0; p < npairs; ++p) {
            if (prow[p] != tid) continue;
            float d = pdist[p]; int c = pcand[p];
            if (d < bd || (d == bd && c < bi)) { bd = d; bi = c; }
        }
        fidx[tid] = bi;
        out[(size_t)NN * DD + 1 + nbase + tid] = (float)bi;
    }
    __syncthreads();

    // ---- gather rows, quantized_st = fl(x + fl(q-x)), fp64 loss ----
    double lacc = 0.0;
    #pragma unroll
    for (int it = 0; it < 16; ++it) {
        int flat = it * BLOCKT + tid;
        int r = flat >> 7;
        int j = (flat & 127) * 4;
        int idx = fidx[r];
        float4 ev = *reinterpret_cast<const float4*>(E + (long)idx * DD + j);
        float xv0 = xsf[(j + 0) * 64 + r];
        float xv1 = xsf[(j + 1) * 64 + r];
        float xv2 = xsf[(j + 2) * 64 + r];
        float xv3 = xsf[(j + 3) * 64 + r];
        float d0 = __fsub_rn(ev.x, xv0);
        float d1 = __fsub_rn(ev.y, xv1);
        float d2 = __fsub_rn(ev.z, xv2);
        float d3 = __fsub_rn(ev.w, xv3);
        float4 st;
        st.x = __fadd_rn(xv0, d0);
        st.y = __fadd_rn(xv1, d1);
        st.z = __fadd_rn(xv2, d2);
        st.w = __fadd_rn(xv3, d3);
        *reinterpret_cast<float4*>(out + (size_t)(nbase + r) * DD + j) = st;
        lacc += (double)d0 * d0 + (double)d1 * d1 + (double)d2 * d2 + (double)d3 * d3;
    }
    #pragma unroll
    for (int off = 32; off; off >>= 1) lacc += __shfl_down(lacc, off, 64);
    if (lane == 0) atomicAdd(loss_acc, lacc);
}

// ================= fallback: passing fp32 kernel (round-2) =================
#define XS_LD 65
#define CODES_PER_WAVE (KK/NWAVES)
#define CHUNK 8
__global__ __launch_bounds__(BLOCKT, 1)
void vq_fp32(const float* __restrict__ x, const float* __restrict__ E,
             const float* __restrict__ se, double* __restrict__ loss_acc,
             float* __restrict__ out) {
    __shared__ float xs[DD * XS_LD];
    __shared__ float smv[NWAVES * ROWS * 2];
    __shared__ int   smi[NWAVES * ROWS * 2];
    __shared__ float Pp[4 * ROWS];
    __shared__ float sxs[ROWS];
    __shared__ int   prow[PMAX];
    __shared__ int   pcand[PMAX];
    __shared__ float pdist[PMAX];
    __shared__ int   pcnt;
    __shared__ int   fidx[ROWS];
    const int tid = threadIdx.x;
    const int blk = blockIdx.x;
    const int b  = blk >> 6;
    const int t0 = (blk & 63) * ROWS;
    const long nbase = (long)b * TT + t0;
    const float* xb = x + (long)b * DD * TT + t0;
    #pragma unroll
    for (int it = 0; it < 16; ++it) {
        int flat = it * BLOCKT + tid;
        int j  = flat >> 4;
        int t4 = (flat & 15) * 4;
        float4 v = *reinterpret_cast<const float4*>(xb + (long)j * TT + t4);
        float* dst = &xs[j * XS_LD + t4];
        dst[0] = v.x; dst[1] = v.y; dst[2] = v.z; dst[3] = v.w;
    }
    if (tid == 0) pcnt = 0;
    __syncthreads();
    if (tid < 4 * ROWS) {
        int r = tid & 63, k = tid >> 6;
        Pp[k * ROWS + r] = pw128_sq_strided(&xs[r] + (k * 128) * XS_LD, XS_LD);
    }
    const int w    = __builtin_amdgcn_readfirstlane(tid >> 6);
    const int lane = tid & 63;
    float m1 = 1e30f, m2 = 1e30f;
    int   i1 = 0,     i2 = 0;
    const int cbase = w * CODES_PER_WAVE;
    for (int ch = 0; ch < CODES_PER_WAVE; ch += CHUNK) {
        const int i0 = cbase + ch;
        const float* Ep = E + (long)i0 * DD;
        float acc[CHUNK];
        #pragma unroll
        for (int c = 0; c < CHUNK; ++c) acc[c] = 0.f;
        for (int j = 0; j < DD; j += 4) {
            float x0 = xs[(j + 0) * XS_LD + lane];
            float x1 = xs[(j + 1) * XS_LD + lane];
            float x2 = xs[(j + 2) * XS_LD + lane];
            float x3 = xs[(j + 3) * XS_LD + lane];
            #pragma unroll
            for (int c = 0; c < CHUNK; ++c) {
                float4 e4 = *reinterpret_cast<const float4*>(&Ep[c * DD + j]);
                acc[c] = fmaf(x0, e4.x, acc[c]);
                acc[c] = fmaf(x1, e4.y, acc[c]);
                acc[c] = fmaf(x2, e4.z, acc[c]);
                acc[c] = fmaf(x3, e4.w, acc[c]);
            }
        }
        #pragma unroll
        for (int c = 0; c < CHUNK; ++c) {
            float s = fmaf(-2.f, acc[c], se[i0 + c]);
            int ii = i0 + c;
            if (s < m1)      { m2 = m1; i2 = i1; m1 = s; i1 = ii; }
            else if (s < m2) { m2 = s;  i2 = ii; }
        }
    }
    smv[(w * ROWS + lane) * 2 + 0] = m1;
    smv[(w * ROWS + lane) * 2 + 1] = m2;
    smi[(w * ROWS + lane) * 2 + 0] = i1;
    smi[(w * ROWS + lane) * 2 + 1] = i2;
    __syncthreads();
    if (tid < ROWS) {
        float sx = __fadd_rn(__fadd_rn(Pp[0 * ROWS + tid], Pp[1 * ROWS + tid]),
                             __fadd_rn(Pp[2 * ROWS + tid], Pp[3 * ROWS + tid]));
        sxs[tid] = sx;
        float m = 1e30f;
        for (int e = 0; e < NWAVES * 2; ++e) {
            float s = smv[((e >> 1) * ROWS + tid) * 2 + (e & 1)];
            if (s < m) m = s;
        }
        float thr = m + MARGIN;
        int pushed = 0;
        for (int e = 0; e < NWAVES * 2 && pushed < CMAX; ++e) {
            float s = smv[((e >> 1) * ROWS + tid) * 2 + (e & 1)];
            if (s <= thr) {
                int pos = atomicAdd(&pcnt, 1);
                if (pos < PMAX) {
                    prow[pos]  = tid;
                    pcand[pos] = smi[((e >> 1) * ROWS + tid) * 2 + (e & 1)];
                    ++pushed;
                }
            }
        }
    }
    __syncthreads();
    const int npairs = (pcnt < PMAX) ? pcnt : PMAX;
    if (tid < npairs) {
        int r = prow[tid], c = pcand[tid];
        const float* Ep = E + (long)c * DD;
        float g = 0.f;
        #pragma unroll 8
        for (int j = 0; j < DD; ++j)
            g = __fmaf_rn(xs[j * XS_LD + r], Ep[j], g);
        float t1 = __fadd_rn(sxs[r], se[c]);
        pdist[tid] = __fsub_rn(t1, __fmul_rn(2.f, g));
    }
    __syncthreads();
    if (tid < ROWS) {
        float bd = 1e30f; int bi = KK;
        for (int p = 0; p < npairs; ++p) {
            if (prow[p] != tid) continue;
            float d = pdist[p]; int c = pcand[p];
            if (d < bd || (d == bd && c < bi)) { bd = d; bi = c; }
        }
        fidx[tid] = bi;
        out[(size_t)NN * DD + 1 + nbase + tid] = (float)bi;
    }
    __syncthreads();
    double lacc = 0.0;
    #pragma unroll
    for (int it = 0; it < 16; ++it) {
        int flat = it * BLOCKT + tid;
        int r = flat >> 7;
        int j = (flat & 127) * 4;
        int idx = fidx[r];
        float4 ev = *reinterpret_cast<const float4*>(E + (long)idx * DD + j);
        float xv0 = xs[(j + 0) * XS_LD + r];
        float xv1 = xs[(j + 1) * XS_LD + r];
        float xv2 = xs[(j + 2) * XS_LD + r];
        float xv3 = xs[(j + 3) * XS_LD + r];
        float d0 = __fsub_rn(ev.x, xv0);
        float d1 = __fsub_rn(ev.y, xv1);
        float d2 = __fsub_rn(ev.z, xv2);
        float d3 = __fsub_rn(ev.w, xv3);
        float4 st;
        st.x = __fadd_rn(xv0, d0);
        st.y = __fadd_rn(xv1, d1);
        st.z = __fadd_rn(xv2, d2);
        st.w = __fadd_rn(xv3, d3);
        *reinterpret_cast<float4*>(out + (size_t)(nbase + r) * DD + j) = st;
        lacc += (double)d0 * d0 + (double)d1 * d1 + (double)d2 * d2 + (double)d3 * d3;
    }
    #pragma unroll
    for (int off = 32; off; off >>= 1) lacc += __shfl_down(lacc, off, 64);
    if (lane == 0) atomicAdd(loss_acc, lacc);
}

// ---------------- loss finalize ----------------
__global__ void finalize_kernel(const double* __restrict__ loss_acc, float* __restrict__ out) {
    if (threadIdx.x == 0 && blockIdx.x == 0) {
        out[(size_t)NN * DD] = (float)(1.25 * (*loss_acc) / ((double)NN * DD));
    }
}

extern "C" void kernel_launch(void* const* d_in, const int* in_sizes, int n_in,
                              void* d_out, int out_size, void* d_ws, size_t ws_size,
                              hipStream_t stream) {
    const float* x = (const float*)d_in[0];
    const float* E = (const float*)d_in[1];
    float* out = (float*)d_out;
    double* loss_acc = (double*)d_ws;                        // 8 B
    float* se = (float*)((char*)d_ws + 64);                  // 4 KB
    unsigned short* Bph = (unsigned short*)((char*)d_ws + 8192);            // 1 MB
    unsigned short* Bpl = (unsigned short*)((char*)d_ws + 8192 + 1048576);  // 1 MB
    const size_t need = 8192 + 2 * 1048576;

    hipMemsetAsync(d_ws, 0, 64, stream);
    enorms_exact<<<4, 256, 0, stream>>>(E, se);
    if (ws_size >= need) {
        pack_e<<<(KK * DD) / 256, 256, 0, stream>>>(E, Bph, Bpl);
        vq_mfma<<<NN / ROWS, BLOCKT, 0, stream>>>(x, E, Bph, Bpl, se, loss_acc, out);
    } else {
        vq_fp32<<<NN / ROWS, BLOCKT, 0, stream>>>(x, E, se, loss_acc, out);
    }
    finalize_kernel<<<1, 64, 0, stream>>>(loss_acc, out);
}

// Round 4
// 450.026 us; speedup vs baseline: 5.9446x; 1.1867x over previous
//
#include <hip/hip_runtime.h>

#define BB 16
#define DD 512
#define TT 4096
#define KK 1024
#define NN (BB*TT)              // 65536 rows
#define ROWS 64                 // t-rows per block
#define BLOCKT 1024             // 16 waves
#define NWAVES 16
#define MARGIN 2e-3f            // candidate margin (err sigma ~4.5e-5 -> 44 sigma)
#define PMAX 512                // max refine pairs per block
#define XLD 65                  // padded leading dim for f32 x tile

typedef __attribute__((ext_vector_type(8))) short short8v;   // 8 bf16
typedef __attribute__((ext_vector_type(4))) float f32x4;

// ---- bf16 split helpers (RNE) ----
__device__ __forceinline__ unsigned short f2bf(float f) {
    unsigned int u = __float_as_uint(f);
    unsigned int r = (u + 0x7fffu + ((u >> 16) & 1u)) >> 16;
    return (unsigned short)r;
}
__device__ __forceinline__ float bf2f(unsigned short b) {
    return __uint_as_float(((unsigned int)b) << 16);
}

// ---- numpy pairwise-sum replication (fp32, squares) — verified passing ----
__device__ __forceinline__ float pw128_sq_strided(const float* a, int stride) {
    float V[16];
    #pragma unroll
    for (int l = 0; l < 16; ++l) {
        float q[8];
        #pragma unroll
        for (int k = 0; k < 8; ++k) {
            float e = a[(l + 16 * k) * stride];
            q[k] = __fmul_rn(e, e);
        }
        V[l] = __fadd_rn(__fadd_rn(__fadd_rn(q[0], q[1]), __fadd_rn(q[2], q[3])),
                         __fadd_rn(__fadd_rn(q[4], q[5]), __fadd_rn(q[6], q[7])));
    }
    float u[8];
    #pragma unroll
    for (int l = 0; l < 8; ++l) u[l] = __fadd_rn(V[l], V[l + 8]);
    float v[4];
    #pragma unroll
    for (int l = 0; l < 4; ++l) v[l] = __fadd_rn(u[l], u[l + 4]);
    return __fadd_rn(__fadd_rn(v[0], v[2]), __fadd_rn(v[1], v[3]));
}
__device__ __forceinline__ float pw512_sq_strided(const float* a, int stride) {
    float p0 = pw128_sq_strided(a, stride);
    float p1 = pw128_sq_strided(a + 128 * stride, stride);
    float p2 = pw128_sq_strided(a + 256 * stride, stride);
    float p3 = pw128_sq_strided(a + 384 * stride, stride);
    return __fadd_rn(__fadd_rn(p0, p1), __fadd_rn(p2, p3));
}

// ---------------- exact ||e||^2 per code row ----------------
__global__ void enorms_exact(const float* __restrict__ E, float* __restrict__ se) {
    int i = blockIdx.x * blockDim.x + threadIdx.x;
    if (i < KK) se[i] = pw512_sq_strided(E + (long)i * DD, 1);
}

// ---------------- pack E (hi bf16 only) into MFMA B-fragment layout --------
// element (code c, k): ntile=c>>4, lane=(c&15)+((k>>3)&3)*16, kk=k>>5, j=k&7
__global__ void pack_e(const float* __restrict__ E, unsigned short* __restrict__ Bph) {
    int i = blockIdx.x * blockDim.x + threadIdx.x;   // 0 .. KK*DD-1
    if (i >= KK * DD) return;
    int c = i >> 9, k = i & 511;
    int lane = (c & 15) + ((k >> 3) & 3) * 16;
    int hw = (((c >> 4) * 16 + (k >> 5)) * 64 + lane) * 8 + (k & 7);
    Bph[hw] = f2bf(E[i]);
}

// ---------------- MFMA main kernel ----------------
__global__ __launch_bounds__(BLOCKT)
void vq_mfma(const float* __restrict__ x, const float* __restrict__ E,
             const unsigned short* __restrict__ Bph,
             const float* __restrict__ se, double* __restrict__ loss_acc,
             float* __restrict__ out) {
    // union: A-packed (hi 64K + lo 64K) during GEMM, then padded f32 x tile
    __shared__ __align__(16) unsigned char uni[DD * XLD * 4];   // 133120 B
    __shared__ float wrowmin[NWAVES * ROWS];
    __shared__ float gthr[ROWS];
    __shared__ float Pp[4 * ROWS];
    __shared__ int   prow[PMAX];
    __shared__ int   pcand[PMAX];
    __shared__ float pdist[PMAX];
    __shared__ int   pcnt;
    __shared__ int   fidx[ROWS];

    const int tid  = threadIdx.x;
    const int w    = tid >> 6;
    const int lane = tid & 63;
    const int blk  = blockIdx.x;
    const int b    = blk >> 6;
    const int t0   = (blk & 63) * ROWS;
    const long nbase = (long)b * TT + t0;
    const float* xb = x + (long)b * DD * TT + t0;

    unsigned short* AhiW = (unsigned short*)uni;
    unsigned short* AloW = (unsigned short*)(uni + 65536);
    float* xsf = (float*)uni;                       // after GEMM: [512][XLD]

    // ---- stage: coalesced dword loads (lane = t), one A-fragment/thread ----
    {
        const float* xbl = xb + lane;
        #pragma unroll
        for (int it = 0; it < 4; ++it) {
            int d0 = (it * NWAVES + w) * 8;
            float v[8];
            #pragma unroll
            for (int jj = 0; jj < 8; ++jj)
                v[jj] = xbl[(long)(d0 + jj) * TT];
            short8v hv, lv;
            #pragma unroll
            for (int jj = 0; jj < 8; ++jj) {
                unsigned short h = f2bf(v[jj]);
                hv[jj] = (short)h;
                lv[jj] = (short)f2bf(v[jj] - bf2f(h));
            }
            int kk = d0 >> 5, lg = (d0 >> 3) & 3;
            int m = lane >> 4, lp = (lane & 15) + lg * 16;
            int hw = (m * 16 + kk) * 64 + lp;
            *(short8v*)(AhiW + (size_t)hw * 8) = hv;   // full-wave b128, conflict-free
            *(short8v*)(AloW + (size_t)hw * 8) = lv;
        }
    }
    if (tid == 0) pcnt = 0;
    __syncthreads();

    // ---- GEMM: this wave's 64 codes, K=512, A hi/lo x B hi (2 MFMA) ----
    f32x4 acc[4][4];
    #pragma unroll
    for (int m = 0; m < 4; ++m)
        #pragma unroll
        for (int n = 0; n < 4; ++n)
            acc[m][n] = (f32x4){0.f, 0.f, 0.f, 0.f};

    const unsigned short* Ah = (const unsigned short*)uni;
    const unsigned short* Al = (const unsigned short*)(uni + 65536);
    const short8v* Bhv = (const short8v*)Bph;

    for (int kk = 0; kk < 16; ++kk) {
        short8v ah[4], al[4];
        #pragma unroll
        for (int m = 0; m < 4; ++m) {
            ah[m] = *(const short8v*)&Ah[((m * 16 + kk) * 64 + lane) * 8];
            al[m] = *(const short8v*)&Al[((m * 16 + kk) * 64 + lane) * 8];
        }
        #pragma unroll
        for (int n = 0; n < 4; ++n) {
            short8v bh = Bhv[((w * 4 + n) * 16 + kk) * 64 + lane];
            #pragma unroll
            for (int m = 0; m < 4; ++m) {
                acc[m][n] = __builtin_amdgcn_mfma_f32_16x16x32_bf16(ah[m], bh, acc[m][n], 0, 0, 0);
                acc[m][n] = __builtin_amdgcn_mfma_f32_16x16x32_bf16(al[m], bh, acc[m][n], 0, 0, 0);
            }
        }
    }

    // ---- epilogue: per-row wave-min (C/D: col=lane&15, row=(lane>>4)*4+reg) ----
    float sef[4];
    #pragma unroll
    for (int n = 0; n < 4; ++n) sef[n] = se[w * 64 + n * 16 + (lane & 15)];

    #pragma unroll
    for (int m = 0; m < 4; ++m) {
        #pragma unroll
        for (int r4 = 0; r4 < 4; ++r4) {
            float mn = 1e30f;
            #pragma unroll
            for (int n = 0; n < 4; ++n)
                mn = fminf(mn, fmaf(-2.f, acc[m][n][r4], sef[n]));
            #pragma unroll
            for (int off = 1; off < 16; off <<= 1)
                mn = fminf(mn, __shfl_xor(mn, off, 64));
            if ((lane & 15) == 0)
                wrowmin[w * ROWS + m * 16 + (lane >> 4) * 4 + r4] = mn;
        }
    }
    __syncthreads();

    if (tid < ROWS) {
        float g = 1e30f;
        #pragma unroll
        for (int ww = 0; ww < NWAVES; ++ww)
            g = fminf(g, wrowmin[ww * ROWS + tid]);
        gthr[tid] = g + MARGIN;
    }
    __syncthreads();

    // ---- push all candidates within margin; refill xsf (f32, padded) ----
    #pragma unroll
    for (int m = 0; m < 4; ++m) {
        #pragma unroll
        for (int r4 = 0; r4 < 4; ++r4) {
            int row = m * 16 + (lane >> 4) * 4 + r4;
            float th = gthr[row];
            #pragma unroll
            for (int n = 0; n < 4; ++n) {
                float sc = fmaf(-2.f, acc[m][n][r4], sef[n]);
                if (sc <= th) {
                    int pos = atomicAdd(&pcnt, 1);
                    if (pos < PMAX) {
                        prow[pos]  = row;
                        pcand[pos] = w * 64 + n * 16 + (lane & 15);
                    }
                }
            }
        }
    }
    __syncthreads();   // A-LDS reads done; pcnt/prow/pcand final

    #pragma unroll
    for (int it = 0; it < 8; ++it) {
        int flat = it * BLOCKT + tid;       // 8192 float4
        int d  = flat >> 4;
        int r4 = (flat & 15) * 4;
        float4 v = *reinterpret_cast<const float4*>(xb + (long)d * TT + r4);
        *reinterpret_cast<float4*>(&xsf[d * XLD + r4]) = v;
    }
    __syncthreads();

    // ---- exact pairwise partials for ||x||^2 ----
    if (tid < 4 * ROWS) {
        int r = tid & 63, k = tid >> 6;
        Pp[k * ROWS + r] = pw128_sq_strided(xsf + r + (k * 128) * XLD, XLD);
    }
    __syncthreads();

    // ---- exact fp32 replay per candidate (numpy semantics) ----
    const int npairs = (pcnt < PMAX) ? pcnt : PMAX;
    if (tid < npairs) {
        int r = prow[tid], c = pcand[tid];
        float sx = __fadd_rn(__fadd_rn(Pp[0 * ROWS + r], Pp[1 * ROWS + r]),
                             __fadd_rn(Pp[2 * ROWS + r], Pp[3 * ROWS + r]));
        const float* Ep = E + (long)c * DD;
        float g = 0.f;
        #pragma unroll 8
        for (int j = 0; j < DD; ++j)
            g = __fmaf_rn(xsf[j * XLD + r], Ep[j], g);
        float t1 = __fadd_rn(sx, se[c]);
        pdist[tid] = __fsub_rn(t1, __fmul_rn(2.f, g));
    }
    __syncthreads();

    // ---- per-row argmin, first-occurrence tie-break ----
    if (tid < ROWS) {
        float bd = 1e30f; int bi = KK;
        for (int p = 0; p < npairs; ++p) {
            if (prow[p] != tid) continue;
            float d = pdist[p]; int c = pcand[p];
            if (d < bd || (d == bd && c < bi)) { bd = d; bi = c; }
        }
        fidx[tid] = bi;
        out[(size_t)NN * DD + 1 + nbase + tid] = (float)bi;
    }
    __syncthreads();

    // ---- gather rows, quantized_st = fl(x + fl(q-x)), fp64 loss ----
    double lacc = 0.0;
    #pragma unroll
    for (int it = 0; it < 8; ++it) {
        int flat = it * BLOCKT + tid;       // 8192 float4 = 64 rows * 128
        int r = flat >> 7;
        int j = (flat & 127) * 4;
        int idx = fidx[r];
        float4 ev = *reinterpret_cast<const float4*>(E + (long)idx * DD + j);
        float xv0 = xsf[(j + 0) * XLD + r];
        float xv1 = xsf[(j + 1) * XLD + r];
        float xv2 = xsf[(j + 2) * XLD + r];
        float xv3 = xsf[(j + 3) * XLD + r];
        float d0 = __fsub_rn(ev.x, xv0);
        float d1 = __fsub_rn(ev.y, xv1);
        float d2 = __fsub_rn(ev.z, xv2);
        float d3 = __fsub_rn(ev.w, xv3);
        float4 st;
        st.x = __fadd_rn(xv0, d0);
        st.y = __fadd_rn(xv1, d1);
        st.z = __fadd_rn(xv2, d2);
        st.w = __fadd_rn(xv3, d3);
        *reinterpret_cast<float4*>(out + (size_t)(nbase + r) * DD + j) = st;
        lacc += (double)d0 * d0 + (double)d1 * d1 + (double)d2 * d2 + (double)d3 * d3;
    }
    #pragma unroll
    for (int off = 32; off; off >>= 1) lacc += __shfl_down(lacc, off, 64);
    if (lane == 0) atomicAdd(loss_acc, lacc);
}

// ---------------- loss finalize ----------------
__global__ void finalize_kernel(const double* __restrict__ loss_acc, float* __restrict__ out) {
    if (threadIdx.x == 0 && blockIdx.x == 0) {
        out[(size_t)NN * DD] = (float)(1.25 * (*loss_acc) / ((double)NN * DD));
    }
}

extern "C" void kernel_launch(void* const* d_in, const int* in_sizes, int n_in,
                              void* d_out, int out_size, void* d_ws, size_t ws_size,
                              hipStream_t stream) {
    const float* x = (const float*)d_in[0];
    const float* E = (const float*)d_in[1];
    float* out = (float*)d_out;
    double* loss_acc = (double*)d_ws;                        // 8 B
    float* se = (float*)((char*)d_ws + 64);                  // 4 KB
    unsigned short* Bph = (unsigned short*)((char*)d_ws + 8192);  // 1 MB

    hipMemsetAsync(d_ws, 0, 64, stream);
    enorms_exact<<<4, 256, 0, stream>>>(E, se);
    pack_e<<<(KK * DD) / 256, 256, 0, stream>>>(E, Bph);
    vq_mfma<<<NN / ROWS, BLOCKT, 0, stream>>>(x, E, Bph, se, loss_acc, out);
    finalize_kernel<<<1, 64, 0, stream>>>(loss_acc, out);
}

// Round 5
// 393.201 us; speedup vs baseline: 6.8037x; 1.1445x over previous
//
#include <hip/hip_runtime.h>

#define BB 16
#define DD 512
#define TT 4096
#define KK 1024
#define NN (BB*TT)              // 65536 rows
#define ROWS 64                 // t-rows per block
#define BLOCKT 1024             // 16 waves
#define NWAVES 16
#define MARGIN 2e-3f            // candidate margin (score sigma ~3e-5 -> >60 sigma)
#define PMAX 512                // max refine pairs per block
#define XLD 65                  // padded leading dim for f32 x tile

typedef __attribute__((ext_vector_type(8))) short short8v;   // 8 bf16
typedef __attribute__((ext_vector_type(4))) float f32x4;

// ---- bf16 helpers (RNE) ----
__device__ __forceinline__ unsigned short f2bf(float f) {
    unsigned int u = __float_as_uint(f);
    unsigned int r = (u + 0x7fffu + ((u >> 16) & 1u)) >> 16;
    return (unsigned short)r;
}

// ---- numpy pairwise-sum replication (fp32, squares) — verified passing ----
__device__ __forceinline__ float pw128_sq_strided(const float* a, int stride) {
    float V[16];
    #pragma unroll
    for (int l = 0; l < 16; ++l) {
        float q[8];
        #pragma unroll
        for (int k = 0; k < 8; ++k) {
            float e = a[(l + 16 * k) * stride];
            q[k] = __fmul_rn(e, e);
        }
        V[l] = __fadd_rn(__fadd_rn(__fadd_rn(q[0], q[1]), __fadd_rn(q[2], q[3])),
                         __fadd_rn(__fadd_rn(q[4], q[5]), __fadd_rn(q[6], q[7])));
    }
    float u[8];
    #pragma unroll
    for (int l = 0; l < 8; ++l) u[l] = __fadd_rn(V[l], V[l + 8]);
    float v[4];
    #pragma unroll
    for (int l = 0; l < 4; ++l) v[l] = __fadd_rn(u[l], u[l + 4]);
    return __fadd_rn(__fadd_rn(v[0], v[2]), __fadd_rn(v[1], v[3]));
}
__device__ __forceinline__ float pw512_sq_strided(const float* a, int stride) {
    float p0 = pw128_sq_strided(a, stride);
    float p1 = pw128_sq_strided(a + 128 * stride, stride);
    float p2 = pw128_sq_strided(a + 256 * stride, stride);
    float p3 = pw128_sq_strided(a + 384 * stride, stride);
    return __fadd_rn(__fadd_rn(p0, p1), __fadd_rn(p2, p3));
}

// ---------------- exact ||e||^2 per code row ----------------
__global__ void enorms_exact(const float* __restrict__ E, float* __restrict__ se) {
    int i = blockIdx.x * blockDim.x + threadIdx.x;
    if (i < KK) se[i] = pw512_sq_strided(E + (long)i * DD, 1);
}

// ---------------- pack E (hi bf16 only) into MFMA B-fragment layout --------
// element (code c, k): ntile=c>>4, lane=(c&15)+((k>>3)&3)*16, kk=k>>5, j=k&7
__global__ void pack_e(const float* __restrict__ E, unsigned short* __restrict__ Bph) {
    int i = blockIdx.x * blockDim.x + threadIdx.x;   // 0 .. KK*DD-1
    if (i >= KK * DD) return;
    int c = i >> 9, k = i & 511;
    int lane = (c & 15) + ((k >> 3) & 3) * 16;
    int hw = (((c >> 4) * 16 + (k >> 5)) * 64 + lane) * 8 + (k & 7);
    Bph[hw] = f2bf(E[i]);
}

// ---- build bf16 A-fragment from resident f32 LDS tile ----
__device__ __forceinline__ short8v build_frag(const float* __restrict__ xsf,
                                              int dbase, int r) {
    union { short8v v; unsigned int wd[4]; } u;
    #pragma unroll
    for (int i = 0; i < 4; ++i) {
        float a = xsf[(dbase + 2 * i    ) * XLD + r];
        float b = xsf[(dbase + 2 * i + 1) * XLD + r];
        unsigned int wd;
        asm("v_cvt_pk_bf16_f32 %0, %1, %2" : "=v"(wd) : "v"(a), "v"(b));
        u.wd[i] = wd;
    }
    return u.v;
}

// ---------------- MFMA main kernel (single x read) ----------------
__global__ __launch_bounds__(BLOCKT)
void vq_mfma(const float* __restrict__ x, const float* __restrict__ E,
             const unsigned short* __restrict__ Bph,
             const float* __restrict__ se, double* __restrict__ loss_acc,
             float* __restrict__ out) {
    __shared__ __align__(16) float xsf[DD * XLD];   // 133120 B, resident all phases
    __shared__ float wrowmin[NWAVES * ROWS];
    __shared__ float gthr[ROWS];
    __shared__ float Pp[4 * ROWS];
    __shared__ int   prow[PMAX];
    __shared__ int   pcand[PMAX];
    __shared__ float pdist[PMAX];
    __shared__ int   pcnt;
    __shared__ int   fidx[ROWS];

    const int tid  = threadIdx.x;
    const int w    = tid >> 6;
    const int lane = tid & 63;
    const int blk  = blockIdx.x;
    const int b    = blk >> 6;
    const int t0   = (blk & 63) * ROWS;
    const long nbase = (long)b * TT + t0;
    const float* xb = x + (long)b * DD * TT + t0;

    // ---- stage f32 x tile [d][r], coalesced float4, 2-way write conflicts ----
    #pragma unroll
    for (int it = 0; it < 8; ++it) {
        int flat = it * BLOCKT + tid;       // 8192 float4
        int d  = flat >> 4;
        int r4 = (flat & 15) * 4;
        float4 v = *reinterpret_cast<const float4*>(xb + (long)d * TT + r4);
        *reinterpret_cast<float4*>(&xsf[d * XLD + r4]) = v;
    }
    if (tid == 0) pcnt = 0;
    __syncthreads();

    // ---- GEMM: this wave's 64 codes, K=512, A=hi(on-the-fly) x B=hi ----
    f32x4 acc[4][4];
    #pragma unroll
    for (int m = 0; m < 4; ++m)
        #pragma unroll
        for (int n = 0; n < 4; ++n)
            acc[m][n] = (f32x4){0.f, 0.f, 0.f, 0.f};

    const short8v* Bhv = (const short8v*)Bph;
    {
        const int lg8 = (lane >> 4) * 8;    // k-subgroup offset within fragment
        const int rl  = lane & 15;
        for (int kk = 0; kk < 16; ++kk) {
            short8v bh[4];
            #pragma unroll
            for (int n = 0; n < 4; ++n)     // issue B loads first (L2 latency cover)
                bh[n] = Bhv[((w * 4 + n) * 16 + kk) * 64 + lane];
            short8v ah[4];
            #pragma unroll
            for (int m = 0; m < 4; ++m)
                ah[m] = build_frag(xsf, kk * 32 + lg8, m * 16 + rl);
            #pragma unroll
            for (int n = 0; n < 4; ++n)
                #pragma unroll
                for (int m = 0; m < 4; ++m)
                    acc[m][n] = __builtin_amdgcn_mfma_f32_16x16x32_bf16(ah[m], bh[n], acc[m][n], 0, 0, 0);
        }
    }

    // ---- epilogue: per-row wave-min (C/D: col=lane&15, row=(lane>>4)*4+reg) ----
    float sef[4];
    #pragma unroll
    for (int n = 0; n < 4; ++n) sef[n] = se[w * 64 + n * 16 + (lane & 15)];

    #pragma unroll
    for (int m = 0; m < 4; ++m) {
        #pragma unroll
        for (int r4 = 0; r4 < 4; ++r4) {
            float mn = 1e30f;
            #pragma unroll
            for (int n = 0; n < 4; ++n)
                mn = fminf(mn, fmaf(-2.f, acc[m][n][r4], sef[n]));
            #pragma unroll
            for (int off = 1; off < 16; off <<= 1)
                mn = fminf(mn, __shfl_xor(mn, off, 64));
            if ((lane & 15) == 0)
                wrowmin[w * ROWS + m * 16 + (lane >> 4) * 4 + r4] = mn;
        }
    }
    __syncthreads();

    if (tid < ROWS) {
        float g = 1e30f;
        #pragma unroll
        for (int ww = 0; ww < NWAVES; ++ww)
            g = fminf(g, wrowmin[ww * ROWS + tid]);
        gthr[tid] = g + MARGIN;
    }
    __syncthreads();

    // ---- push candidates within margin; ||x||^2 partials (fused phase) ----
    #pragma unroll
    for (int m = 0; m < 4; ++m) {
        #pragma unroll
        for (int r4 = 0; r4 < 4; ++r4) {
            int row = m * 16 + (lane >> 4) * 4 + r4;
            float th = gthr[row];
            #pragma unroll
            for (int n = 0; n < 4; ++n) {
                float sc = fmaf(-2.f, acc[m][n][r4], sef[n]);
                if (sc <= th) {
                    int pos = atomicAdd(&pcnt, 1);
                    if (pos < PMAX) {
                        prow[pos]  = row;
                        pcand[pos] = w * 64 + n * 16 + (lane & 15);
                    }
                }
            }
        }
    }
    if (tid < 4 * ROWS) {
        int r = tid & 63, k = tid >> 6;
        Pp[k * ROWS + r] = pw128_sq_strided(xsf + r + (k * 128) * XLD, XLD);
    }
    __syncthreads();

    // ---- exact fp32 replay per candidate (numpy semantics), wave-spread ----
    const int npairs = (pcnt < PMAX) ? pcnt : PMAX;
    {
        int p = lane * NWAVES + w;          // spread pairs across all 16 waves
        if (p < npairs) {
            int r = prow[p], c = pcand[p];
            float sx = __fadd_rn(__fadd_rn(Pp[0 * ROWS + r], Pp[1 * ROWS + r]),
                                 __fadd_rn(Pp[2 * ROWS + r], Pp[3 * ROWS + r]));
            const float* Ep = E + (long)c * DD;
            float g = 0.f;
            #pragma unroll 8
            for (int j = 0; j < DD; ++j)
                g = __fmaf_rn(xsf[j * XLD + r], Ep[j], g);
            float t1 = __fadd_rn(sx, se[c]);
            pdist[p] = __fsub_rn(t1, __fmul_rn(2.f, g));
        }
    }
    __syncthreads();

    // ---- per-row argmin, first-occurrence tie-break ----
    if (tid < ROWS) {
        float bd = 1e30f; int bi = KK;
        for (int p = 0; p < npairs; ++p) {
            if (prow[p] != tid) continue;
            float d = pdist[p]; int c = pcand[p];
            if (d < bd || (d == bd && c < bi)) { bd = d; bi = c; }
        }
        fidx[tid] = bi;
        out[(size_t)NN * DD + 1 + nbase + tid] = (float)bi;
    }
    __syncthreads();

    // ---- gather rows, quantized_st = fl(x + fl(q-x)), fp64 loss ----
    double lacc = 0.0;
    #pragma unroll
    for (int it = 0; it < 8; ++it) {
        int flat = it * BLOCKT + tid;       // 8192 float4 = 64 rows * 128
        int r = flat >> 7;
        int j = (flat & 127) * 4;
        int idx = fidx[r];
        float4 ev = *reinterpret_cast<const float4*>(E + (long)idx * DD + j);
        float xv0 = xsf[(j + 0) * XLD + r];
        float xv1 = xsf[(j + 1) * XLD + r];
        float xv2 = xsf[(j + 2) * XLD + r];
        float xv3 = xsf[(j + 3) * XLD + r];
        float d0 = __fsub_rn(ev.x, xv0);
        float d1 = __fsub_rn(ev.y, xv1);
        float d2 = __fsub_rn(ev.z, xv2);
        float d3 = __fsub_rn(ev.w, xv3);
        float4 st;
        st.x = __fadd_rn(xv0, d0);
        st.y = __fadd_rn(xv1, d1);
        st.z = __fadd_rn(xv2, d2);
        st.w = __fadd_rn(xv3, d3);
        *reinterpret_cast<float4*>(out + (size_t)(nbase + r) * DD + j) = st;
        lacc += (double)d0 * d0 + (double)d1 * d1 + (double)d2 * d2 + (double)d3 * d3;
    }
    #pragma unroll
    for (int off = 32; off; off >>= 1) lacc += __shfl_down(lacc, off, 64);
    if (lane == 0) atomicAdd(loss_acc, lacc);
}

// ---------------- loss finalize ----------------
__global__ void finalize_kernel(const double* __restrict__ loss_acc, float* __restrict__ out) {
    if (threadIdx.x == 0 && blockIdx.x == 0) {
        out[(size_t)NN * DD] = (float)(1.25 * (*loss_acc) / ((double)NN * DD));
    }
}

extern "C" void kernel_launch(void* const* d_in, const int* in_sizes, int n_in,
                              void* d_out, int out_size, void* d_ws, size_t ws_size,
                              hipStream_t stream) {
    const float* x = (const float*)d_in[0];
    const float* E = (const float*)d_in[1];
    float* out = (float*)d_out;
    double* loss_acc = (double*)d_ws;                        // 8 B
    float* se = (float*)((char*)d_ws + 64);                  // 4 KB
    unsigned short* Bph = (unsigned short*)((char*)d_ws + 8192);  // 1 MB

    hipMemsetAsync(d_ws, 0, 64, stream);
    enorms_exact<<<4, 256, 0, stream>>>(E, se);
    pack_e<<<(KK * DD) / 256, 256, 0, stream>>>(E, Bph);
    vq_mfma<<<NN / ROWS, BLOCKT, 0, stream>>>(x, E, Bph, se, loss_acc, out);
    finalize_kernel<<<1, 64, 0, stream>>>(loss_acc, out);
}